// Round 1
// baseline (24799.249 us; speedup 1.0000x reference)
//
#include <hip/hip_runtime.h>
#include <hip/hip_bf16.h>
#include <stdint.h>

// Problem constants
#define NN 8192
#define MM 4096
#define DD 256
#define REGC 0.1f
#define FIC 0.8333333333333334f   // tau/(tau+reg) = 0.5/0.6
#define AMARG (1.0f/8192.0f)
#define BMARG (1.0f/4096.0f)
#define NIT 250

typedef __bf16 bf16x8_t __attribute__((ext_vector_type(8)));
typedef float f32x4_t __attribute__((ext_vector_type(4)));
typedef unsigned short us8_t __attribute__((ext_vector_type(8)));

__device__ __forceinline__ float bf2f(unsigned short h) {
    return __uint_as_float(((unsigned int)h) << 16);
}
__device__ __forceinline__ unsigned short f2bf(float f) {
    unsigned int u = __float_as_uint(f);
    u = u + 0x7FFFu + ((u >> 16) & 1u);   // RNE
    return (unsigned short)(u >> 16);
}
__device__ __forceinline__ float wsum(float v) {
    #pragma unroll
    for (int m = 32; m >= 1; m >>= 1) v += __shfl_xor(v, m, 64);
    return v;
}
__device__ __forceinline__ float wmaxr(float v) {
    #pragma unroll
    for (int m = 32; m >= 1; m >>= 1) v = fmaxf(v, __shfl_xor(v, m, 64));
    return v;
}

// ---------------- init: zero t[1], cmax, dist slot ----------------
__global__ void init_kernel(float* __restrict__ t3, unsigned int* __restrict__ cmaxu,
                            float* __restrict__ out) {
    int tid = threadIdx.x; // 256 threads
    #pragma unroll
    for (int q = 0; q < 16; ++q) t3[MM + tid + q*256] = 0.0f;
    if (tid == 0) { *cmaxu = 0u; out[(size_t)NN*DD] = 0.0f; }
}

// ---------------- normalize rows of src/tgt; emit f32 + bf16 + tgt^T(bf16) ----------------
__global__ void norm_kernel(const float* __restrict__ src, const float* __restrict__ tgt,
                            float* __restrict__ srcn, float* __restrict__ tgtn,
                            unsigned short* __restrict__ srcb, unsigned short* __restrict__ tgtb,
                            unsigned short* __restrict__ tgtT) {
    int b = blockIdx.x, l = threadIdx.x;      // 64 threads = 1 wave per row
    bool is_src = b < NN;
    int r = is_src ? b : b - NN;
    const float* in = is_src ? src : tgt;
    float* outf = is_src ? srcn : tgtn;
    unsigned short* outb = is_src ? srcb : tgtb;

    f32x4_t x = *(const f32x4_t*)(in + (size_t)r*DD + l*4);
    float s = x[0]+x[1]+x[2]+x[3];
    s = wsum(s);
    float mean = s * (1.0f/(float)DD);
    float c0=x[0]-mean, c1=x[1]-mean, c2=x[2]-mean, c3=x[3]-mean;
    float ss = c0*c0+c1*c1+c2*c2+c3*c3;
    ss = wsum(ss);
    float scale = 1.0f / fmaxf(sqrtf(ss), 1e-8f);
    f32x4_t o; o[0]=c0*scale; o[1]=c1*scale; o[2]=c2*scale; o[3]=c3*scale;
    *(f32x4_t*)(outf + (size_t)r*DD + l*4) = o;
    unsigned short b0=f2bf(o[0]), b1=f2bf(o[1]), b2=f2bf(o[2]), b3=f2bf(o[3]);
    unsigned long long pk = (unsigned long long)b0 | ((unsigned long long)b1<<16)
                          | ((unsigned long long)b2<<32) | ((unsigned long long)b3<<48);
    *(unsigned long long*)(outb + (size_t)r*DD + l*4) = pk;
    if (!is_src) {
        tgtT[(size_t)(l*4+0)*MM + r] = b0;
        tgtT[(size_t)(l*4+1)*MM + r] = b1;
        tgtT[(size_t)(l*4+2)*MM + r] = b2;
        tgtT[(size_t)(l*4+3)*MM + r] = b3;
    }
}

// ---------------- dots = srcn @ tgtn^T (MFMA bf16), store bf16 dots into K buffer,
// ----------------  fused global max of cost = 2-2*dot ----------------
__launch_bounds__(256)
__global__ void dot_kernel(const unsigned short* __restrict__ srcb,
                           const unsigned short* __restrict__ tgtb,
                           unsigned short* __restrict__ Kb,
                           unsigned int* __restrict__ cmaxu) {
    __shared__ unsigned short Al[64][40];   // +8 pad: breaks bank conflicts
    __shared__ unsigned short Bl[64][40];
    __shared__ float redsh[4];
    int tid = threadIdx.x;
    int bi = blockIdx.x & 127, bj = blockIdx.x >> 7;   // 128 x 64 tiles of 64x64
    int i0 = bi * 64, j0 = bj * 64;
    int l = tid & 63, wid = tid >> 6;
    int wm = wid >> 1, wn = wid & 1;
    int fr = l & 15, kc = (l >> 4) * 8;
    f32x4_t acc[2][2] = {};
    int sr = tid >> 2, sc = (tid & 3) * 8;
    for (int kk = 0; kk < DD; kk += 32) {
        __syncthreads();
        *(uint4*)(&Al[sr][sc]) = *(const uint4*)(srcb + (size_t)(i0+sr)*DD + kk + sc);
        *(uint4*)(&Bl[sr][sc]) = *(const uint4*)(tgtb + (size_t)(j0+sr)*DD + kk + sc);
        __syncthreads();
        bf16x8_t a0 = *(const bf16x8_t*)(&Al[wm*32 + fr][kc]);
        bf16x8_t a1 = *(const bf16x8_t*)(&Al[wm*32 + 16 + fr][kc]);
        bf16x8_t b0 = *(const bf16x8_t*)(&Bl[wn*32 + fr][kc]);
        bf16x8_t b1 = *(const bf16x8_t*)(&Bl[wn*32 + 16 + fr][kc]);
        acc[0][0] = __builtin_amdgcn_mfma_f32_16x16x32_bf16(a0, b0, acc[0][0], 0, 0, 0);
        acc[0][1] = __builtin_amdgcn_mfma_f32_16x16x32_bf16(a0, b1, acc[0][1], 0, 0, 0);
        acc[1][0] = __builtin_amdgcn_mfma_f32_16x16x32_bf16(a1, b0, acc[1][0], 0, 0, 0);
        acc[1][1] = __builtin_amdgcn_mfma_f32_16x16x32_bf16(a1, b1, acc[1][1], 0, 0, 0);
    }
    int rq = (l >> 4) * 4;
    float mx = 0.0f;
    #pragma unroll
    for (int fm = 0; fm < 2; ++fm) {
        #pragma unroll
        for (int fn = 0; fn < 2; ++fn) {
            #pragma unroll
            for (int q = 0; q < 4; ++q) {
                int row = i0 + wm*32 + fm*16 + rq + q;    // C/D: row=(l>>4)*4+q
                int col = j0 + wn*32 + fn*16 + fr;        //      col=l&15
                float d = acc[fm][fn][q];
                mx = fmaxf(mx, 2.0f - 2.0f*d);
                Kb[(size_t)row*MM + col] = f2bf(d);
            }
        }
    }
    mx = wmaxr(mx);
    if (l == 0) redsh[wid] = mx;
    __syncthreads();
    if (tid == 0) {
        float m = fmaxf(fmaxf(redsh[0], redsh[1]), fmaxf(redsh[2], redsh[3]));
        atomicMax(cmaxu, __float_as_uint(m));   // cost >= 0 -> uint order == float order
    }
}

// ---------------- in-place: bf16 dot -> bf16 K = exp(-max(0,2-2dot)/(reg*cmax)) ----------------
__global__ void kbuild_kernel(unsigned short* __restrict__ Kb,
                              const unsigned int* __restrict__ cmaxu) {
    float cmax = __uint_as_float(*cmaxu);
    float nbeta = -1.0f / (REGC * cmax);
    size_t stride = (size_t)gridDim.x * blockDim.x;
    for (size_t c = (size_t)blockIdx.x*blockDim.x + threadIdx.x; c < (size_t)NN*MM/8; c += stride) {
        us8_t d = *(const us8_t*)(Kb + c*8);
        us8_t o;
        #pragma unroll
        for (int q = 0; q < 8; ++q) {
            float C = fmaxf(2.0f - 2.0f*bf2f(d[q]), 0.0f);
            o[q] = f2bf(__expf(C * nbeta));
        }
        *(us8_t*)(Kb + c*8) = o;
    }
}

// ---------------- one Sinkhorn iteration, single fused pass over K ----------------
// reads t_in (prev col sums) -> v; computes u; accumulates t_out = K^T u (atomics);
// zeros t_zero for the NEXT iteration (3-buffer rotation).
__launch_bounds__(512)
__global__ void sink_kernel(const unsigned short* __restrict__ Kb,
                            const float* __restrict__ t_in,
                            float* __restrict__ t_out,
                            float* __restrict__ t_zero,
                            float* __restrict__ u_out,
                            int first) {
    __shared__ float sred[8][8];
    __shared__ float u_lds[8];
    int tid = threadIdx.x, l = tid & 63, w = tid >> 6;   // 8 waves; wave w owns j-slice
    int jb = (w << 9) + (l << 3);                        // 8 contiguous j per lane
    if (blockIdx.x == 0) {
        #pragma unroll
        for (int q = 0; q < 8; ++q) t_zero[tid + q*512] = 0.0f;
    }
    float vreg[8];
    if (first) {
        #pragma unroll
        for (int q = 0; q < 8; ++q) vreg[q] = 1.0f;
    } else {
        f32x4_t va = *(const f32x4_t*)(t_in + jb);
        f32x4_t vb = *(const f32x4_t*)(t_in + jb + 4);
        #pragma unroll
        for (int q = 0; q < 8; ++q) {
            float t = (q < 4) ? va[q] : vb[q-4];
            vreg[q] = __expf(FIC * __logf(BMARG / t));   // v = (b/t)^fi
        }
    }
    float tacc[8] = {0,0,0,0,0,0,0,0};
    int row0 = blockIdx.x * 32;                           // 256 blocks * 32 rows
    for (int g = 0; g < 4; ++g) {
        int rbase = row0 + g*8;
        us8_t kreg[8];
        float part[8];
        #pragma unroll
        for (int r = 0; r < 8; ++r) {
            kreg[r] = *(const us8_t*)(Kb + (size_t)(rbase + r)*MM + jb);
            float p = 0.0f;
            #pragma unroll
            for (int q = 0; q < 8; ++q) p += bf2f(kreg[r][q]) * vreg[q];
            part[r] = p;
        }
        #pragma unroll
        for (int r = 0; r < 8; ++r) {
            part[r] = wsum(part[r]);
            if (l == r) sred[w][r] = part[r];   // static reg index; lane r writes row r
        }
        __syncthreads();
        if (tid < 8) {
            float s = 0.0f;
            #pragma unroll
            for (int ww = 0; ww < 8; ++ww) s += sred[ww][tid];
            float uu = __expf(FIC * __logf(AMARG / s));  // u = (a/s)^fi
            u_lds[tid] = uu;
            u_out[rbase + tid] = uu;
        }
        __syncthreads();
        #pragma unroll
        for (int r = 0; r < 8; ++r) {
            float uu = u_lds[r];
            #pragma unroll
            for (int q = 0; q < 8; ++q) tacc[q] += bf2f(kreg[r][q]) * uu;
        }
    }
    #pragma unroll
    for (int q = 0; q < 8; ++q) atomicAdd(&t_out[jb + q], tacc[q]);
}

// ---------------- final v from last col sums ----------------
__global__ void vfin_kernel(const float* __restrict__ t_in, float* __restrict__ vf) {
    int j = blockIdx.x * 256 + threadIdx.x;
    vf[j] = __expf(FIC * __logf(BMARG / t_in[j]));
}

// ---------------- finalize: flow = u*K*v ; dist = sum(C*flow) ; out = srcn + flow@tgtn ----------------
__launch_bounds__(256)
__global__ void final_kernel(const unsigned short* __restrict__ Kb,
                             const float* __restrict__ u,
                             const float* __restrict__ vf,
                             const unsigned short* __restrict__ tgtT,
                             const float* __restrict__ srcn,
                             const unsigned int* __restrict__ cmaxu,
                             float* __restrict__ out) {
    __shared__ float dsh[2];
    int tid = threadIdx.x, l = tid & 63, wid = tid >> 6;
    int it = wid & 1, dh = wid >> 1;              // 2 i-tiles x 2 d-halves per block
    int i0 = blockIdx.x * 32 + it * 16;
    int fr = l & 15, kq = l >> 4;
    int row = i0 + fr;
    float u_l = u[row];
    const unsigned short* Krow = Kb + (size_t)row * MM;
    f32x4_t acc[8] = {};
    float distp = 0.0f;
    for (int jc = 0; jc < MM; jc += 32) {
        int off = jc + kq*8;
        us8_t kv = *(const us8_t*)(Krow + off);
        f32x4_t va = *(const f32x4_t*)(vf + off);
        f32x4_t vb = *(const f32x4_t*)(vf + off + 4);
        us8_t fbv;
        #pragma unroll
        for (int q = 0; q < 8; ++q) {
            float kf = bf2f(kv[q]);
            float vv = (q < 4) ? va[q] : vb[q-4];
            float fl = u_l * kf * vv;             // flow element (f32)
            if (dh == 0) distp -= __logf(kf) * fl; // dist (count each (i,j) once)
            fbv[q] = f2bf(fl);
        }
        bf16x8_t afr = __builtin_bit_cast(bf16x8_t, fbv);
        #pragma unroll
        for (int f = 0; f < 8; ++f) {
            int drow = (dh*8 + f)*16 + fr;
            bf16x8_t bfr = *(const bf16x8_t*)(tgtT + (size_t)drow*MM + off);
            acc[f] = __builtin_amdgcn_mfma_f32_16x16x32_bf16(afr, bfr, acc[f], 0, 0, 0);
        }
    }
    float cmax = __uint_as_float(*cmaxu);
    int rq = kq * 4;
    #pragma unroll
    for (int f = 0; f < 8; ++f) {
        #pragma unroll
        for (int q = 0; q < 4; ++q) {
            size_t idx = (size_t)(i0 + rq + q) * DD + (dh*8 + f)*16 + fr;
            out[idx] = srcn[idx] + acc[f][q];
        }
    }
    if (dh == 0) {
        distp = wsum(distp);
        if (l == 0) dsh[wid] = distp;   // wid 0 or 1
    }
    __syncthreads();
    if (tid == 0) atomicAdd(out + (size_t)NN*DD, (dsh[0] + dsh[1]) * (REGC * cmax));
}

// ---------------- host ----------------
extern "C" void kernel_launch(void* const* d_in, const int* in_sizes, int n_in,
                              void* d_out, int out_size, void* d_ws, size_t ws_size,
                              hipStream_t stream) {
    const float* src = (const float*)d_in[0];
    const float* tgt = (const float*)d_in[1];
    float* out = (float*)d_out;
    char* ws = (char*)d_ws;

    constexpr size_t OFF_SRCN = 0;                       // 8192*256*4
    constexpr size_t OFF_TGTN = 8388608;                 // 4096*256*4
    constexpr size_t OFF_SRCB = 12582912;                // 8192*256*2
    constexpr size_t OFF_TGTB = 16777216;                // 4096*256*2
    constexpr size_t OFF_TGTT = 18874368;                // 256*4096*2
    constexpr size_t OFF_K    = 20971520;                // 8192*4096*2
    constexpr size_t OFF_U    = 88080384;                // 8192*4
    constexpr size_t OFF_T3   = 88113152;                // 3*4096*4
    constexpr size_t OFF_VF   = 88162304;                // 4096*4
    constexpr size_t OFF_CMAX = 88178688;                // 4

    float* srcn = (float*)(ws + OFF_SRCN);
    float* tgtn = (float*)(ws + OFF_TGTN);
    unsigned short* srcb = (unsigned short*)(ws + OFF_SRCB);
    unsigned short* tgtb = (unsigned short*)(ws + OFF_TGTB);
    unsigned short* tgtT = (unsigned short*)(ws + OFF_TGTT);
    unsigned short* Kb   = (unsigned short*)(ws + OFF_K);
    float* u    = (float*)(ws + OFF_U);
    float* t3   = (float*)(ws + OFF_T3);
    float* vf   = (float*)(ws + OFF_VF);
    unsigned int* cmaxu = (unsigned int*)(ws + OFF_CMAX);

    init_kernel<<<1, 256, 0, stream>>>(t3, cmaxu, out);
    norm_kernel<<<NN + MM, 64, 0, stream>>>(src, tgt, srcn, tgtn, srcb, tgtb, tgtT);
    dot_kernel<<<(NN/64)*(MM/64), 256, 0, stream>>>(srcb, tgtb, Kb, cmaxu);
    kbuild_kernel<<<2048, 256, 0, stream>>>(Kb, cmaxu);
    for (int k = 0; k < NIT; ++k) {
        sink_kernel<<<NN/32, 512, 0, stream>>>(Kb,
                                               t3 + (size_t)(k % 3) * MM,
                                               t3 + (size_t)((k + 1) % 3) * MM,
                                               t3 + (size_t)((k + 2) % 3) * MM,
                                               u, k == 0 ? 1 : 0);
    }
    vfin_kernel<<<MM/256, 256, 0, stream>>>(t3 + (size_t)(NIT % 3) * MM, vf);
    final_kernel<<<NN/32, 256, 0, stream>>>(Kb, u, vf, tgtT, srcn, cmaxu, out);
}

// Round 2
// 15068.254 us; speedup vs baseline: 1.6458x; 1.6458x over previous
//
#include <hip/hip_runtime.h>
#include <hip/hip_bf16.h>
#include <stdint.h>

// Problem constants
#define NN 8192
#define MM 4096
#define DD 256
#define REGC 0.1f
#define FIC 0.8333333333333334f   // tau/(tau+reg) = 0.5/0.6
#define AMARG (1.0f/8192.0f)
#define BMARG (1.0f/4096.0f)
#define NIT 100                   // contraction rate fi=0.833 -> fi^100 ~ 1e-8, converged

typedef __bf16 bf16x8_t __attribute__((ext_vector_type(8)));
typedef float f32x4_t __attribute__((ext_vector_type(4)));
typedef unsigned short us8_t __attribute__((ext_vector_type(8)));

__device__ __forceinline__ float bf2f(unsigned short h) {
    return __uint_as_float(((unsigned int)h) << 16);
}
__device__ __forceinline__ unsigned short f2bf(float f) {
    unsigned int u = __float_as_uint(f);
    u = u + 0x7FFFu + ((u >> 16) & 1u);   // RNE
    return (unsigned short)(u >> 16);
}
__device__ __forceinline__ float wsum(float v) {
    #pragma unroll
    for (int m = 32; m >= 1; m >>= 1) v += __shfl_xor(v, m, 64);
    return v;
}
__device__ __forceinline__ float wmaxr(float v) {
    #pragma unroll
    for (int m = 32; m >= 1; m >>= 1) v = fmaxf(v, __shfl_xor(v, m, 64));
    return v;
}

// ---------------- init: zero t[1], cmax, dist slot ----------------
__global__ void init_kernel(float* __restrict__ t3, unsigned int* __restrict__ cmaxu,
                            float* __restrict__ out) {
    int tid = threadIdx.x; // 256 threads
    #pragma unroll
    for (int q = 0; q < 16; ++q) t3[MM + tid + q*256] = 0.0f;
    if (tid == 0) { *cmaxu = 0u; out[(size_t)NN*DD] = 0.0f; }
}

// ---------------- normalize rows of src/tgt; emit f32 + bf16 + tgt^T(bf16) ----------------
__global__ void norm_kernel(const float* __restrict__ src, const float* __restrict__ tgt,
                            float* __restrict__ srcn, float* __restrict__ tgtn,
                            unsigned short* __restrict__ srcb, unsigned short* __restrict__ tgtb,
                            unsigned short* __restrict__ tgtT) {
    int b = blockIdx.x, l = threadIdx.x;      // 64 threads = 1 wave per row
    bool is_src = b < NN;
    int r = is_src ? b : b - NN;
    const float* in = is_src ? src : tgt;
    float* outf = is_src ? srcn : tgtn;
    unsigned short* outb = is_src ? srcb : tgtb;

    f32x4_t x = *(const f32x4_t*)(in + (size_t)r*DD + l*4);
    float s = x[0]+x[1]+x[2]+x[3];
    s = wsum(s);
    float mean = s * (1.0f/(float)DD);
    float c0=x[0]-mean, c1=x[1]-mean, c2=x[2]-mean, c3=x[3]-mean;
    float ss = c0*c0+c1*c1+c2*c2+c3*c3;
    ss = wsum(ss);
    float scale = 1.0f / fmaxf(sqrtf(ss), 1e-8f);
    f32x4_t o; o[0]=c0*scale; o[1]=c1*scale; o[2]=c2*scale; o[3]=c3*scale;
    *(f32x4_t*)(outf + (size_t)r*DD + l*4) = o;
    unsigned short b0=f2bf(o[0]), b1=f2bf(o[1]), b2=f2bf(o[2]), b3=f2bf(o[3]);
    unsigned long long pk = (unsigned long long)b0 | ((unsigned long long)b1<<16)
                          | ((unsigned long long)b2<<32) | ((unsigned long long)b3<<48);
    *(unsigned long long*)(outb + (size_t)r*DD + l*4) = pk;
    if (!is_src) {
        tgtT[(size_t)(l*4+0)*MM + r] = b0;
        tgtT[(size_t)(l*4+1)*MM + r] = b1;
        tgtT[(size_t)(l*4+2)*MM + r] = b2;
        tgtT[(size_t)(l*4+3)*MM + r] = b3;
    }
}

// ---------------- dots = srcn @ tgtn^T (MFMA bf16), store bf16 dots into K buffer,
// ----------------  fused global max of cost = 2-2*dot ----------------
__launch_bounds__(256)
__global__ void dot_kernel(const unsigned short* __restrict__ srcb,
                           const unsigned short* __restrict__ tgtb,
                           unsigned short* __restrict__ Kb,
                           unsigned int* __restrict__ cmaxu) {
    __shared__ unsigned short Al[64][40];   // +8 pad: breaks bank conflicts
    __shared__ unsigned short Bl[64][40];
    __shared__ float redsh[4];
    int tid = threadIdx.x;
    int bi = blockIdx.x & 127, bj = blockIdx.x >> 7;   // 128 x 64 tiles of 64x64
    int i0 = bi * 64, j0 = bj * 64;
    int l = tid & 63, wid = tid >> 6;
    int wm = wid >> 1, wn = wid & 1;
    int fr = l & 15, kc = (l >> 4) * 8;
    f32x4_t acc[2][2] = {};
    int sr = tid >> 2, sc = (tid & 3) * 8;
    for (int kk = 0; kk < DD; kk += 32) {
        __syncthreads();
        *(uint4*)(&Al[sr][sc]) = *(const uint4*)(srcb + (size_t)(i0+sr)*DD + kk + sc);
        *(uint4*)(&Bl[sr][sc]) = *(const uint4*)(tgtb + (size_t)(j0+sr)*DD + kk + sc);
        __syncthreads();
        bf16x8_t a0 = *(const bf16x8_t*)(&Al[wm*32 + fr][kc]);
        bf16x8_t a1 = *(const bf16x8_t*)(&Al[wm*32 + 16 + fr][kc]);
        bf16x8_t b0 = *(const bf16x8_t*)(&Bl[wn*32 + fr][kc]);
        bf16x8_t b1 = *(const bf16x8_t*)(&Bl[wn*32 + 16 + fr][kc]);
        acc[0][0] = __builtin_amdgcn_mfma_f32_16x16x32_bf16(a0, b0, acc[0][0], 0, 0, 0);
        acc[0][1] = __builtin_amdgcn_mfma_f32_16x16x32_bf16(a0, b1, acc[0][1], 0, 0, 0);
        acc[1][0] = __builtin_amdgcn_mfma_f32_16x16x32_bf16(a1, b0, acc[1][0], 0, 0, 0);
        acc[1][1] = __builtin_amdgcn_mfma_f32_16x16x32_bf16(a1, b1, acc[1][1], 0, 0, 0);
    }
    int rq = (l >> 4) * 4;
    float mx = 0.0f;
    #pragma unroll
    for (int fm = 0; fm < 2; ++fm) {
        #pragma unroll
        for (int fn = 0; fn < 2; ++fn) {
            #pragma unroll
            for (int q = 0; q < 4; ++q) {
                int row = i0 + wm*32 + fm*16 + rq + q;    // C/D: row=(l>>4)*4+q
                int col = j0 + wn*32 + fn*16 + fr;        //      col=l&15
                float d = acc[fm][fn][q];
                mx = fmaxf(mx, 2.0f - 2.0f*d);
                Kb[(size_t)row*MM + col] = f2bf(d);
            }
        }
    }
    mx = wmaxr(mx);
    if (l == 0) redsh[wid] = mx;
    __syncthreads();
    if (tid == 0) {
        float m = fmaxf(fmaxf(redsh[0], redsh[1]), fmaxf(redsh[2], redsh[3]));
        atomicMax(cmaxu, __float_as_uint(m));   // cost >= 0 -> uint order == float order
    }
}

// ---------------- in-place: bf16 dot -> bf16 K = exp(-max(0,2-2dot)/(reg*cmax)) ----------------
__global__ void kbuild_kernel(unsigned short* __restrict__ Kb,
                              const unsigned int* __restrict__ cmaxu) {
    float cmax = __uint_as_float(*cmaxu);
    float nbeta = -1.0f / (REGC * cmax);
    size_t stride = (size_t)gridDim.x * blockDim.x;
    for (size_t c = (size_t)blockIdx.x*blockDim.x + threadIdx.x; c < (size_t)NN*MM/8; c += stride) {
        us8_t d = *(const us8_t*)(Kb + c*8);
        us8_t o;
        #pragma unroll
        for (int q = 0; q < 8; ++q) {
            float C = fmaxf(2.0f - 2.0f*bf2f(d[q]), 0.0f);
            o[q] = f2bf(__expf(C * nbeta));
        }
        *(us8_t*)(Kb + c*8) = o;
    }
}

// ---------------- one Sinkhorn iteration, deep-MLP restructure ----------------
// Block: 16 rows, 512 threads (8 waves), 512 blocks (2 blocks/CU, 4 waves/SIMD).
// Phase 0: v = (b/t_in)^fi -> LDS (all blocks; block 0 also zeroes t_zero).
// Phase 1: wave w owns rows {2w, 2w+1}; ALL 16 chunk-loads issued upfront (deep MLP);
//          one wsum pair; u computed redundantly per-lane (no cross-wave funnel).
// Phase 2: wave w owns a 512-col slice; re-reads the block's L2-hot slab with all 16
//          row-loads in flight; 8 atomicAdds per lane into t_out.
__launch_bounds__(512, 4)
__global__ void sink_kernel(const unsigned short* __restrict__ Kb,
                            const float* __restrict__ t_in,
                            float* __restrict__ t_out,
                            float* __restrict__ t_zero,
                            float* __restrict__ u_out,
                            int first) {
    __shared__ float v_lds[MM];
    __shared__ float u_lds[16];
    int tid = threadIdx.x, l = tid & 63, w = tid >> 6;
    int row0 = blockIdx.x * 16;

    // ---- phase 0
    if (first) {
        #pragma unroll
        for (int q = 0; q < 8; ++q) v_lds[tid*8 + q] = 1.0f;
    } else {
        f32x4_t t0 = *(const f32x4_t*)(t_in + tid*8);
        f32x4_t t1 = *(const f32x4_t*)(t_in + tid*8 + 4);
        #pragma unroll
        for (int q = 0; q < 8; ++q) {
            float t = (q < 4) ? t0[q] : t1[q-4];
            v_lds[tid*8 + q] = __expf(FIC * __logf(BMARG / t));
        }
    }
    if (blockIdx.x == 0) {
        #pragma unroll
        for (int q = 0; q < 8; ++q) t_zero[tid + q*512] = 0.0f;
    }
    __syncthreads();

    // ---- phase 1: rows ra, ra+1 across all 4096 cols
    int ra = row0 + 2*w;
    const unsigned short* KA = Kb + (size_t)ra*MM;
    const unsigned short* KB = Kb + (size_t)(ra+1)*MM;
    uint4 ka[8], kb[8];
    #pragma unroll
    for (int c = 0; c < 8; ++c) {
        ka[c] = *(const uint4*)(KA + c*512 + l*8);
        kb[c] = *(const uint4*)(KB + c*512 + l*8);
    }
    float acc0 = 0.0f, acc1 = 0.0f;
    #pragma unroll
    for (int c = 0; c < 8; ++c) {
        const float* vp = v_lds + c*512 + l*8;
        f32x4_t v0 = *(const f32x4_t*)vp;
        f32x4_t v1 = *(const f32x4_t*)(vp + 4);
        uint4 A = ka[c], B = kb[c];
        acc0 += __uint_as_float(A.x << 16)          * v0[0];
        acc0 += __uint_as_float(A.x & 0xffff0000u)  * v0[1];
        acc0 += __uint_as_float(A.y << 16)          * v0[2];
        acc0 += __uint_as_float(A.y & 0xffff0000u)  * v0[3];
        acc0 += __uint_as_float(A.z << 16)          * v1[0];
        acc0 += __uint_as_float(A.z & 0xffff0000u)  * v1[1];
        acc0 += __uint_as_float(A.w << 16)          * v1[2];
        acc0 += __uint_as_float(A.w & 0xffff0000u)  * v1[3];
        acc1 += __uint_as_float(B.x << 16)          * v0[0];
        acc1 += __uint_as_float(B.x & 0xffff0000u)  * v0[1];
        acc1 += __uint_as_float(B.y << 16)          * v0[2];
        acc1 += __uint_as_float(B.y & 0xffff0000u)  * v0[3];
        acc1 += __uint_as_float(B.z << 16)          * v1[0];
        acc1 += __uint_as_float(B.z & 0xffff0000u)  * v1[1];
        acc1 += __uint_as_float(B.w << 16)          * v1[2];
        acc1 += __uint_as_float(B.w & 0xffff0000u)  * v1[3];
    }
    acc0 = wsum(acc0); acc1 = wsum(acc1);
    float u0 = __expf(FIC * __logf(AMARG / acc0));   // redundant per-lane, no funnel
    float u1 = __expf(FIC * __logf(AMARG / acc1));
    if (l == 0) {
        u_lds[2*w] = u0; u_lds[2*w+1] = u1;
        u_out[ra] = u0; u_out[ra+1] = u1;
    }
    __syncthreads();

    // ---- phase 2: col slice [w*512, w*512+512), rows row0..row0+15
    int jb = w*512 + l*8;
    uint4 kc[16];
    #pragma unroll
    for (int r = 0; r < 16; ++r)
        kc[r] = *(const uint4*)(Kb + (size_t)(row0 + r)*MM + jb);
    f32x4_t uu[4];
    #pragma unroll
    for (int g = 0; g < 4; ++g) uu[g] = *(const f32x4_t*)(u_lds + g*4);
    float tacc[8] = {0,0,0,0,0,0,0,0};
    #pragma unroll
    for (int r = 0; r < 16; ++r) {
        float ur = uu[r >> 2][r & 3];
        uint4 Kv = kc[r];
        tacc[0] += __uint_as_float(Kv.x << 16)         * ur;
        tacc[1] += __uint_as_float(Kv.x & 0xffff0000u) * ur;
        tacc[2] += __uint_as_float(Kv.y << 16)         * ur;
        tacc[3] += __uint_as_float(Kv.y & 0xffff0000u) * ur;
        tacc[4] += __uint_as_float(Kv.z << 16)         * ur;
        tacc[5] += __uint_as_float(Kv.z & 0xffff0000u) * ur;
        tacc[6] += __uint_as_float(Kv.w << 16)         * ur;
        tacc[7] += __uint_as_float(Kv.w & 0xffff0000u) * ur;
    }
    #pragma unroll
    for (int q = 0; q < 8; ++q) atomicAdd(&t_out[jb + q], tacc[q]);
}

// ---------------- final v from last col sums ----------------
__global__ void vfin_kernel(const float* __restrict__ t_in, float* __restrict__ vf) {
    int j = blockIdx.x * 256 + threadIdx.x;
    vf[j] = __expf(FIC * __logf(BMARG / t_in[j]));
}

// ---------------- finalize: flow = u*K*v ; dist = sum(C*flow) ; out = srcn + flow@tgtn ----------------
__launch_bounds__(256)
__global__ void final_kernel(const unsigned short* __restrict__ Kb,
                             const float* __restrict__ u,
                             const float* __restrict__ vf,
                             const unsigned short* __restrict__ tgtT,
                             const float* __restrict__ srcn,
                             const unsigned int* __restrict__ cmaxu,
                             float* __restrict__ out) {
    __shared__ float dsh[2];
    int tid = threadIdx.x, l = tid & 63, wid = tid >> 6;
    int it = wid & 1, dh = wid >> 1;              // 2 i-tiles x 2 d-halves per block
    int i0 = blockIdx.x * 32 + it * 16;
    int fr = l & 15, kq = l >> 4;
    int row = i0 + fr;
    float u_l = u[row];
    const unsigned short* Krow = Kb + (size_t)row * MM;
    f32x4_t acc[8] = {};
    float distp = 0.0f;
    for (int jc = 0; jc < MM; jc += 32) {
        int off = jc + kq*8;
        us8_t kv = *(const us8_t*)(Krow + off);
        f32x4_t va = *(const f32x4_t*)(vf + off);
        f32x4_t vb = *(const f32x4_t*)(vf + off + 4);
        us8_t fbv;
        #pragma unroll
        for (int q = 0; q < 8; ++q) {
            float kf = bf2f(kv[q]);
            float vv = (q < 4) ? va[q] : vb[q-4];
            float fl = u_l * kf * vv;             // flow element (f32)
            if (dh == 0) distp -= __logf(kf) * fl; // dist (count each (i,j) once)
            fbv[q] = f2bf(fl);
        }
        bf16x8_t afr = __builtin_bit_cast(bf16x8_t, fbv);
        #pragma unroll
        for (int f = 0; f < 8; ++f) {
            int drow = (dh*8 + f)*16 + fr;
            bf16x8_t bfr = *(const bf16x8_t*)(tgtT + (size_t)drow*MM + off);
            acc[f] = __builtin_amdgcn_mfma_f32_16x16x32_bf16(afr, bfr, acc[f], 0, 0, 0);
        }
    }
    float cmax = __uint_as_float(*cmaxu);
    int rq = kq * 4;
    #pragma unroll
    for (int f = 0; f < 8; ++f) {
        #pragma unroll
        for (int q = 0; q < 4; ++q) {
            size_t idx = (size_t)(i0 + rq + q) * DD + (dh*8 + f)*16 + fr;
            out[idx] = srcn[idx] + acc[f][q];
        }
    }
    if (dh == 0) {
        distp = wsum(distp);
        if (l == 0) dsh[wid] = distp;   // wid 0 or 1
    }
    __syncthreads();
    if (tid == 0) atomicAdd(out + (size_t)NN*DD, (dsh[0] + dsh[1]) * (REGC * cmax));
}

// ---------------- host ----------------
extern "C" void kernel_launch(void* const* d_in, const int* in_sizes, int n_in,
                              void* d_out, int out_size, void* d_ws, size_t ws_size,
                              hipStream_t stream) {
    const float* src = (const float*)d_in[0];
    const float* tgt = (const float*)d_in[1];
    float* out = (float*)d_out;
    char* ws = (char*)d_ws;

    constexpr size_t OFF_SRCN = 0;                       // 8192*256*4
    constexpr size_t OFF_TGTN = 8388608;                 // 4096*256*4
    constexpr size_t OFF_SRCB = 12582912;                // 8192*256*2
    constexpr size_t OFF_TGTB = 16777216;                // 4096*256*2
    constexpr size_t OFF_TGTT = 18874368;                // 256*4096*2
    constexpr size_t OFF_K    = 20971520;                // 8192*4096*2
    constexpr size_t OFF_U    = 88080384;                // 8192*4
    constexpr size_t OFF_T3   = 88113152;                // 3*4096*4
    constexpr size_t OFF_VF   = 88162304;                // 4096*4
    constexpr size_t OFF_CMAX = 88178688;                // 4

    float* srcn = (float*)(ws + OFF_SRCN);
    float* tgtn = (float*)(ws + OFF_TGTN);
    unsigned short* srcb = (unsigned short*)(ws + OFF_SRCB);
    unsigned short* tgtb = (unsigned short*)(ws + OFF_TGTB);
    unsigned short* tgtT = (unsigned short*)(ws + OFF_TGTT);
    unsigned short* Kb   = (unsigned short*)(ws + OFF_K);
    float* u    = (float*)(ws + OFF_U);
    float* t3   = (float*)(ws + OFF_T3);
    float* vf   = (float*)(ws + OFF_VF);
    unsigned int* cmaxu = (unsigned int*)(ws + OFF_CMAX);

    init_kernel<<<1, 256, 0, stream>>>(t3, cmaxu, out);
    norm_kernel<<<NN + MM, 64, 0, stream>>>(src, tgt, srcn, tgtn, srcb, tgtb, tgtT);
    dot_kernel<<<(NN/64)*(MM/64), 256, 0, stream>>>(srcb, tgtb, Kb, cmaxu);
    kbuild_kernel<<<2048, 256, 0, stream>>>(Kb, cmaxu);
    for (int k = 0; k < NIT; ++k) {
        sink_kernel<<<NN/16, 512, 0, stream>>>(Kb,
                                               t3 + (size_t)(k % 3) * MM,
                                               t3 + (size_t)((k + 1) % 3) * MM,
                                               t3 + (size_t)((k + 2) % 3) * MM,
                                               u, k == 0 ? 1 : 0);
    }
    vfin_kernel<<<MM/256, 256, 0, stream>>>(t3 + (size_t)(NIT % 3) * MM, vf);
    final_kernel<<<NN/32, 256, 0, stream>>>(Kb, u, vf, tgtT, srcn, cmaxu, out);
}

// Round 3
// 1856.746 us; speedup vs baseline: 13.3563x; 8.1154x over previous
//
#include <hip/hip_runtime.h>
#include <hip/hip_bf16.h>
#include <stdint.h>

// Problem constants
#define NN 8192
#define MM 4096
#define DD 256
#define REGC 0.1f
#define FIC 0.8333333333333334f   // tau/(tau+reg) = 0.5/0.6
#define AMARG (1.0f/8192.0f)
#define BMARG (1.0f/4096.0f)
#define NIT 48                    // full-iter map is fi^2=0.694-Lipschitz; 0.694^48 ~ 2e-8

typedef __bf16 bf16x8_t __attribute__((ext_vector_type(8)));
typedef float f32x4_t __attribute__((ext_vector_type(4)));
typedef unsigned short us8_t __attribute__((ext_vector_type(8)));

__device__ __forceinline__ float bf2f(unsigned short h) {
    return __uint_as_float(((unsigned int)h) << 16);
}
__device__ __forceinline__ unsigned short f2bf(float f) {
    unsigned int u = __float_as_uint(f);
    u = u + 0x7FFFu + ((u >> 16) & 1u);   // RNE
    return (unsigned short)(u >> 16);
}
__device__ __forceinline__ float wsum(float v) {
    #pragma unroll
    for (int m = 32; m >= 1; m >>= 1) v += __shfl_xor(v, m, 64);
    return v;
}
__device__ __forceinline__ float wmaxr(float v) {
    #pragma unroll
    for (int m = 32; m >= 1; m >>= 1) v = fmaxf(v, __shfl_xor(v, m, 64));
    return v;
}
// acc += dot(bf16x8 packed in uint4, f32 v[8])
__device__ __forceinline__ void dot8(float& acc, uint4 A, f32x4_t v0, f32x4_t v1) {
    acc += __uint_as_float(A.x << 16)          * v0[0];
    acc += __uint_as_float(A.x & 0xffff0000u)  * v0[1];
    acc += __uint_as_float(A.y << 16)          * v0[2];
    acc += __uint_as_float(A.y & 0xffff0000u)  * v0[3];
    acc += __uint_as_float(A.z << 16)          * v1[0];
    acc += __uint_as_float(A.z & 0xffff0000u)  * v1[1];
    acc += __uint_as_float(A.w << 16)          * v1[2];
    acc += __uint_as_float(A.w & 0xffff0000u)  * v1[3];
}

// ---------------- init: zero cmax + dist slot ----------------
__global__ void init_kernel(unsigned int* __restrict__ cmaxu, float* __restrict__ out) {
    if (threadIdx.x == 0) { *cmaxu = 0u; out[(size_t)NN*DD] = 0.0f; }
}

// ---------------- normalize rows; emit srcn(f32) + srcb/tgtb(bf16) + tgtT(bf16) ----------------
__global__ void norm_kernel(const float* __restrict__ src, const float* __restrict__ tgt,
                            float* __restrict__ srcn,
                            unsigned short* __restrict__ srcb, unsigned short* __restrict__ tgtb,
                            unsigned short* __restrict__ tgtT) {
    int b = blockIdx.x, l = threadIdx.x;      // 64 threads = 1 wave per row
    bool is_src = b < NN;
    int r = is_src ? b : b - NN;
    const float* in = is_src ? src : tgt;
    unsigned short* outb = is_src ? srcb : tgtb;

    f32x4_t x = *(const f32x4_t*)(in + (size_t)r*DD + l*4);
    float s = x[0]+x[1]+x[2]+x[3];
    s = wsum(s);
    float mean = s * (1.0f/(float)DD);
    float c0=x[0]-mean, c1=x[1]-mean, c2=x[2]-mean, c3=x[3]-mean;
    float ss = c0*c0+c1*c1+c2*c2+c3*c3;
    ss = wsum(ss);
    float scale = 1.0f / fmaxf(sqrtf(ss), 1e-8f);
    f32x4_t o; o[0]=c0*scale; o[1]=c1*scale; o[2]=c2*scale; o[3]=c3*scale;
    unsigned short b0=f2bf(o[0]), b1=f2bf(o[1]), b2=f2bf(o[2]), b3=f2bf(o[3]);
    unsigned long long pk = (unsigned long long)b0 | ((unsigned long long)b1<<16)
                          | ((unsigned long long)b2<<32) | ((unsigned long long)b3<<48);
    *(unsigned long long*)(outb + (size_t)r*DD + l*4) = pk;
    if (is_src) {
        *(f32x4_t*)(srcn + (size_t)r*DD + l*4) = o;
    } else {
        tgtT[(size_t)(l*4+0)*MM + r] = b0;
        tgtT[(size_t)(l*4+1)*MM + r] = b1;
        tgtT[(size_t)(l*4+2)*MM + r] = b2;
        tgtT[(size_t)(l*4+3)*MM + r] = b3;
    }
}

// ---------------- dots = srcn @ tgtn^T (MFMA bf16) -> Kb ; global max cost ----------------
__launch_bounds__(256)
__global__ void dot_kernel(const unsigned short* __restrict__ srcb,
                           const unsigned short* __restrict__ tgtb,
                           unsigned short* __restrict__ Kb,
                           unsigned int* __restrict__ cmaxu) {
    __shared__ unsigned short Al[64][40];
    __shared__ unsigned short Bl[64][40];
    __shared__ float redsh[4];
    int tid = threadIdx.x;
    int bi = blockIdx.x & 127, bj = blockIdx.x >> 7;
    int i0 = bi * 64, j0 = bj * 64;
    int l = tid & 63, wid = tid >> 6;
    int wm = wid >> 1, wn = wid & 1;
    int fr = l & 15, kc = (l >> 4) * 8;
    f32x4_t acc[2][2] = {};
    int sr = tid >> 2, sc = (tid & 3) * 8;
    for (int kk = 0; kk < DD; kk += 32) {
        __syncthreads();
        *(uint4*)(&Al[sr][sc]) = *(const uint4*)(srcb + (size_t)(i0+sr)*DD + kk + sc);
        *(uint4*)(&Bl[sr][sc]) = *(const uint4*)(tgtb + (size_t)(j0+sr)*DD + kk + sc);
        __syncthreads();
        bf16x8_t a0 = *(const bf16x8_t*)(&Al[wm*32 + fr][kc]);
        bf16x8_t a1 = *(const bf16x8_t*)(&Al[wm*32 + 16 + fr][kc]);
        bf16x8_t b0 = *(const bf16x8_t*)(&Bl[wn*32 + fr][kc]);
        bf16x8_t b1 = *(const bf16x8_t*)(&Bl[wn*32 + 16 + fr][kc]);
        acc[0][0] = __builtin_amdgcn_mfma_f32_16x16x32_bf16(a0, b0, acc[0][0], 0, 0, 0);
        acc[0][1] = __builtin_amdgcn_mfma_f32_16x16x32_bf16(a0, b1, acc[0][1], 0, 0, 0);
        acc[1][0] = __builtin_amdgcn_mfma_f32_16x16x32_bf16(a1, b0, acc[1][0], 0, 0, 0);
        acc[1][1] = __builtin_amdgcn_mfma_f32_16x16x32_bf16(a1, b1, acc[1][1], 0, 0, 0);
    }
    int rq = (l >> 4) * 4;
    float mx = 0.0f;
    #pragma unroll
    for (int fm = 0; fm < 2; ++fm) {
        #pragma unroll
        for (int fn = 0; fn < 2; ++fn) {
            #pragma unroll
            for (int q = 0; q < 4; ++q) {
                int row = i0 + wm*32 + fm*16 + rq + q;
                int col = j0 + wn*32 + fn*16 + fr;
                float d = acc[fm][fn][q];
                mx = fmaxf(mx, 2.0f - 2.0f*d);
                Kb[(size_t)row*MM + col] = f2bf(d);
            }
        }
    }
    mx = wmaxr(mx);
    if (l == 0) redsh[wid] = mx;
    __syncthreads();
    if (tid == 0) {
        float m = fmaxf(fmaxf(redsh[0], redsh[1]), fmaxf(redsh[2], redsh[3]));
        atomicMax(cmaxu, __float_as_uint(m));
    }
}

// ---------------- in-place: bf16 dot -> bf16 K = exp(-max(0,2-2dot)/(reg*cmax)) ----------------
__global__ void kbuild_kernel(unsigned short* __restrict__ Kb,
                              const unsigned int* __restrict__ cmaxu) {
    float cmax = __uint_as_float(*cmaxu);
    float nbeta = -1.0f / (REGC * cmax);
    size_t stride = (size_t)gridDim.x * blockDim.x;
    for (size_t c = (size_t)blockIdx.x*blockDim.x + threadIdx.x; c < (size_t)NN*MM/8; c += stride) {
        us8_t d = *(const us8_t*)(Kb + c*8);
        us8_t o;
        #pragma unroll
        for (int q = 0; q < 8; ++q) {
            float C = fmaxf(2.0f - 2.0f*bf2f(d[q]), 0.0f);
            o[q] = f2bf(__expf(C * nbeta));
        }
        *(us8_t*)(Kb + c*8) = o;
    }
}

// ---------------- u-pass: u_i = (a / sum_j K_ij v_j)^fi  (block-local, no atomics) ----------------
// 512 blocks x 512 thr; 16 rows/block; each wave owns 2 full rows, 16 uint4 loads upfront.
__launch_bounds__(512)
__global__ void upass_kernel(const unsigned short* __restrict__ Kb,
                             const float* __restrict__ vin,
                             float* __restrict__ uout, int first) {
    __shared__ float v_lds[MM];
    int tid = threadIdx.x, l = tid & 63, w = tid >> 6;
    int row0 = blockIdx.x * 16;
    if (first) {
        #pragma unroll
        for (int q = 0; q < 8; ++q) v_lds[tid*8 + q] = 1.0f;
    } else {
        f32x4_t a0 = *(const f32x4_t*)(vin + tid*8);
        f32x4_t a1 = *(const f32x4_t*)(vin + tid*8 + 4);
        *(f32x4_t*)(v_lds + tid*8) = a0;
        *(f32x4_t*)(v_lds + tid*8 + 4) = a1;
    }
    __syncthreads();
    int ra = row0 + 2*w;
    const unsigned short* KA = Kb + (size_t)ra*MM;
    const unsigned short* KB2 = KA + MM;
    uint4 ka[8], kb[8];
    #pragma unroll
    for (int c = 0; c < 8; ++c) ka[c] = *(const uint4*)(KA + c*512 + l*8);
    #pragma unroll
    for (int c = 0; c < 8; ++c) kb[c] = *(const uint4*)(KB2 + c*512 + l*8);
    float acc0 = 0.0f, acc1 = 0.0f;
    #pragma unroll
    for (int c = 0; c < 8; ++c) {
        const float* vp = v_lds + c*512 + l*8;
        f32x4_t v0 = *(const f32x4_t*)vp;
        f32x4_t v1 = *(const f32x4_t*)(vp + 4);
        dot8(acc0, ka[c], v0, v1);
        dot8(acc1, kb[c], v0, v1);
    }
    acc0 = wsum(acc0); acc1 = wsum(acc1);
    if (l == 0) {
        uout[ra]     = __expf(FIC * __logf(AMARG / acc0));
        uout[ra + 1] = __expf(FIC * __logf(AMARG / acc1));
    }
}

// ---------------- col-partials: part[b][j] = sum_{i in block b} K_ij u_i  (plain stores) ----------------
// 512 blocks x 512 thr; block owns 16 rows; wave owns a 512-col slice; 16 uint4 loads upfront.
__launch_bounds__(512)
__global__ void colpart_kernel(const unsigned short* __restrict__ Kb,
                               const float* __restrict__ u,
                               float* __restrict__ part) {
    __shared__ float u_lds[16];
    int tid = threadIdx.x, l = tid & 63, w = tid >> 6;
    int row0 = blockIdx.x * 16;
    if (tid < 16) u_lds[tid] = u[row0 + tid];
    __syncthreads();
    int jb = w*512 + l*8;
    uint4 kc[16];
    #pragma unroll
    for (int r = 0; r < 16; ++r)
        kc[r] = *(const uint4*)(Kb + (size_t)(row0 + r)*MM + jb);
    float tacc[8] = {0,0,0,0,0,0,0,0};
    #pragma unroll
    for (int r = 0; r < 16; ++r) {
        float ur = u_lds[r];
        uint4 Kv = kc[r];
        tacc[0] += __uint_as_float(Kv.x << 16)         * ur;
        tacc[1] += __uint_as_float(Kv.x & 0xffff0000u) * ur;
        tacc[2] += __uint_as_float(Kv.y << 16)         * ur;
        tacc[3] += __uint_as_float(Kv.y & 0xffff0000u) * ur;
        tacc[4] += __uint_as_float(Kv.z << 16)         * ur;
        tacc[5] += __uint_as_float(Kv.z & 0xffff0000u) * ur;
        tacc[6] += __uint_as_float(Kv.w << 16)         * ur;
        tacc[7] += __uint_as_float(Kv.w & 0xffff0000u) * ur;
    }
    float* pp = part + (size_t)blockIdx.x*MM + jb;
    f32x4_t o0; o0[0]=tacc[0]; o0[1]=tacc[1]; o0[2]=tacc[2]; o0[3]=tacc[3];
    f32x4_t o1; o1[0]=tacc[4]; o1[1]=tacc[5]; o1[2]=tacc[6]; o1[3]=tacc[7];
    *(f32x4_t*)pp = o0;
    *(f32x4_t*)(pp + 4) = o1;
}

// ---------------- v-reduce: v_j = (b / sum_p part[p][j])^fi ----------------
// 64 blocks x 512 thr; block owns 64 j; wave w sums p in [w*64, w*64+64).
__launch_bounds__(512)
__global__ void vred_kernel(const float* __restrict__ part, float* __restrict__ vout) {
    __shared__ float red[8][64];
    int tid = threadIdx.x, l = tid & 63, w = tid >> 6;
    int j = blockIdx.x * 64 + l;
    float s = 0.0f;
    #pragma unroll 8
    for (int p = w*64; p < w*64 + 64; ++p) s += part[(size_t)p*MM + j];
    red[w][l] = s;
    __syncthreads();
    if (w == 0) {
        float t = red[0][l];
        #pragma unroll
        for (int ww = 1; ww < 8; ++ww) t += red[ww][l];
        vout[j] = __expf(FIC * __logf(BMARG / t));
    }
}

// ---------------- WT[d][j] = v_j * tgtT[d][j] (bf16) ----------------
__global__ void wt_kernel(const unsigned short* __restrict__ tgtT,
                          const float* __restrict__ v,
                          unsigned short* __restrict__ WT) {
    int idx = blockIdx.x * 256 + threadIdx.x;   // 512 blocks x 256 thr = 131072 chunks
    int d = idx >> 9, jc = (idx & 511) * 8;
    us8_t tv = *(const us8_t*)(tgtT + (size_t)d*MM + jc);
    f32x4_t v0 = *(const f32x4_t*)(v + jc);
    f32x4_t v1 = *(const f32x4_t*)(v + jc + 4);
    us8_t o;
    #pragma unroll
    for (int q = 0; q < 8; ++q) {
        float vv = (q < 4) ? v0[q] : v1[q-4];
        o[q] = f2bf(bf2f(tv[q]) * vv);
    }
    *(us8_t*)(WT + (size_t)d*MM + jc) = o;
}

// ---------------- finalize: out = srcn + diag(u) (K @ WT^T)  ; dist fused ----------------
// 256 blocks x 512 thr (8 waves = 2 row-halves x 4 d-quarters); K read once.
__launch_bounds__(512)
__global__ void final_kernel(const unsigned short* __restrict__ Kb,
                             const float* __restrict__ u,
                             const float* __restrict__ v,
                             const unsigned short* __restrict__ WT,
                             const float* __restrict__ srcn,
                             const unsigned int* __restrict__ cmaxu,
                             float* __restrict__ out) {
    __shared__ float dsh[2];
    int tid = threadIdx.x, l = tid & 63, wid = tid >> 6;
    int it = wid & 1, dq = wid >> 1;          // 2 row-halves x 4 d-quarters
    int ih = blockIdx.x * 32 + it * 16;
    int fr = l & 15, kq = l >> 4;
    int row = ih + fr;
    const unsigned short* Krow = Kb + (size_t)row * MM;
    float u_l = u[row];
    f32x4_t acc[4] = {};
    float distp = 0.0f;
    for (int jc = 0; jc < MM; jc += 32) {
        int off = jc + kq*8;
        us8_t kv = *(const us8_t*)(Krow + off);
        bf16x8_t afr = __builtin_bit_cast(bf16x8_t, kv);
        #pragma unroll
        for (int f = 0; f < 4; ++f) {
            int drow = (dq*4 + f)*16 + fr;
            bf16x8_t bfr = *(const bf16x8_t*)(WT + (size_t)drow*MM + off);
            acc[f] = __builtin_amdgcn_mfma_f32_16x16x32_bf16(afr, bfr, acc[f], 0, 0, 0);
        }
        if (dq == 0) {
            f32x4_t va = *(const f32x4_t*)(v + off);
            f32x4_t vb = *(const f32x4_t*)(v + off + 4);
            #pragma unroll
            for (int q = 0; q < 8; ++q) {
                float kf = bf2f(kv[q]);
                float vv = (q < 4) ? va[q] : vb[q-4];
                distp -= __logf(kf) * kf * vv;
            }
        }
    }
    float cmax = __uint_as_float(*cmaxu);
    int rq = kq * 4;
    float uq[4];
    #pragma unroll
    for (int q = 0; q < 4; ++q) uq[q] = u[ih + rq + q];
    #pragma unroll
    for (int f = 0; f < 4; ++f) {
        int d = (dq*4 + f)*16 + fr;
        #pragma unroll
        for (int q = 0; q < 4; ++q) {
            size_t idx = (size_t)(ih + rq + q)*DD + d;
            out[idx] = srcn[idx] + uq[q]*acc[f][q];
        }
    }
    if (dq == 0) {
        distp *= u_l;
        distp = wsum(distp);
        if (l == 0) dsh[it] = distp;
    }
    __syncthreads();
    if (tid == 0) atomicAdd(out + (size_t)NN*DD, (dsh[0] + dsh[1]) * (REGC * cmax));
}

// ---------------- host ----------------
extern "C" void kernel_launch(void* const* d_in, const int* in_sizes, int n_in,
                              void* d_out, int out_size, void* d_ws, size_t ws_size,
                              hipStream_t stream) {
    const float* src = (const float*)d_in[0];
    const float* tgt = (const float*)d_in[1];
    float* out = (float*)d_out;
    char* ws = (char*)d_ws;

    constexpr size_t OFF_SRCN = 0;                        // 8192*256*4  = 8388608
    constexpr size_t OFF_SRCB = 8388608;                  // 8192*256*2  = 4194304
    constexpr size_t OFF_TGTB = 12582912;                 // 4096*256*2  = 2097152
    constexpr size_t OFF_TGTT = 14680064;                 // 256*4096*2  = 2097152
    constexpr size_t OFF_WT   = 16777216;                 // 256*4096*2  = 2097152
    constexpr size_t OFF_K    = 18874368;                 // 8192*4096*2 = 67108864
    constexpr size_t OFF_PART = 85983232;                 // 512*4096*4  = 8388608
    constexpr size_t OFF_U    = 94371840;                 // 8192*4
    constexpr size_t OFF_V    = 94404608;                 // 4096*4
    constexpr size_t OFF_CMAX = 94420992;                 // 4

    float* srcn = (float*)(ws + OFF_SRCN);
    unsigned short* srcb = (unsigned short*)(ws + OFF_SRCB);
    unsigned short* tgtb = (unsigned short*)(ws + OFF_TGTB);
    unsigned short* tgtT = (unsigned short*)(ws + OFF_TGTT);
    unsigned short* WT   = (unsigned short*)(ws + OFF_WT);
    unsigned short* Kb   = (unsigned short*)(ws + OFF_K);
    float* part = (float*)(ws + OFF_PART);
    float* u    = (float*)(ws + OFF_U);
    float* v    = (float*)(ws + OFF_V);
    unsigned int* cmaxu = (unsigned int*)(ws + OFF_CMAX);

    init_kernel<<<1, 64, 0, stream>>>(cmaxu, out);
    norm_kernel<<<NN + MM, 64, 0, stream>>>(src, tgt, srcn, srcb, tgtb, tgtT);
    dot_kernel<<<(NN/64)*(MM/64), 256, 0, stream>>>(srcb, tgtb, Kb, cmaxu);
    kbuild_kernel<<<2048, 256, 0, stream>>>(Kb, cmaxu);
    for (int k = 0; k < NIT; ++k) {
        upass_kernel<<<NN/16, 512, 0, stream>>>(Kb, v, u, k == 0 ? 1 : 0);
        colpart_kernel<<<NN/16, 512, 0, stream>>>(Kb, u, part);
        vred_kernel<<<MM/64, 512, 0, stream>>>(part, v);
    }
    wt_kernel<<<512, 256, 0, stream>>>(tgtT, v, WT);
    final_kernel<<<NN/32, 512, 0, stream>>>(Kb, u, v, WT, srcn, cmaxu, out);
}